// Round 6
// baseline (1146.264 us; speedup 1.0000x reference)
//
#include <hip/hip_runtime.h>
#include <cstdint>

#define UNITS 512
#define NB 256
#define NT 128
#define ND 512
#define G3 1536

#define SEQ_ELEMS (16777216L)              // 256*128*512
#define STATE_OFF (SEQ_ELEMS)
#define STEP_OFF  (SEQ_ELEMS + 131072L)

#define BGS 16
#define ROWS_PER_BG 16

#define WS_H_OFF    65536
#define H_ELEMS     131072L                // 256*512 per generation; 4 gens

typedef unsigned short u16;
typedef short short8 __attribute__((ext_vector_type(8)));
typedef float f32x4 __attribute__((ext_vector_type(4)));
typedef unsigned int u32;

__device__ __forceinline__ u16 f2b(float f) {
  u32 x = __float_as_uint(f);
  u32 r = (x + 0x7FFFu + ((x >> 16) & 1u)) >> 16;
  return (u16)r;
}
__device__ __forceinline__ float b2f(u16 u) {
  return __uint_as_float(((u32)u) << 16);
}

template<int MODE>
__device__ __forceinline__ float ldf(const void* p, long idx) {
  if (MODE) return b2f(((const u16*)p)[idx]);
  else      return ((const float*)p)[idx];
}

// ---- coherent (LLC) primitives: per-access sc0/sc1, no L2 flushes ----
__device__ __forceinline__ void store_h_coherent(const u16* p, u16 v) {
  u32 vv = v;
  asm volatile("global_store_short %0, %1, off sc0 sc1"
               :: "v"(p), "v"(vv) : "memory");
}
__device__ __forceinline__ void store_sent16(const u16* p) {
  f32x4 s;
  s[0] = __uint_as_float(0xFFFFFFFFu); s[1] = s[0]; s[2] = s[0]; s[3] = s[0];
  asm volatile("global_store_dwordx4 %0, %1, off sc0 sc1"
               :: "v"(p), "v"(s) : "memory");
}

// 16 pipelined 16B coherent loads + single drain (gfx950: offset BEFORE sc flags)
__device__ __forceinline__ void load_h16_coherent(const u16* p, short8 hf[16]) {
  asm volatile(
    "global_load_dwordx4 %0, %16, off sc0 sc1\n\t"
    "global_load_dwordx4 %1, %16, off offset:64 sc0 sc1\n\t"
    "global_load_dwordx4 %2, %16, off offset:128 sc0 sc1\n\t"
    "global_load_dwordx4 %3, %16, off offset:192 sc0 sc1\n\t"
    "global_load_dwordx4 %4, %16, off offset:256 sc0 sc1\n\t"
    "global_load_dwordx4 %5, %16, off offset:320 sc0 sc1\n\t"
    "global_load_dwordx4 %6, %16, off offset:384 sc0 sc1\n\t"
    "global_load_dwordx4 %7, %16, off offset:448 sc0 sc1\n\t"
    "global_load_dwordx4 %8, %16, off offset:512 sc0 sc1\n\t"
    "global_load_dwordx4 %9, %16, off offset:576 sc0 sc1\n\t"
    "global_load_dwordx4 %10, %16, off offset:640 sc0 sc1\n\t"
    "global_load_dwordx4 %11, %16, off offset:704 sc0 sc1\n\t"
    "global_load_dwordx4 %12, %16, off offset:768 sc0 sc1\n\t"
    "global_load_dwordx4 %13, %16, off offset:832 sc0 sc1\n\t"
    "global_load_dwordx4 %14, %16, off offset:896 sc0 sc1\n\t"
    "global_load_dwordx4 %15, %16, off offset:960 sc0 sc1\n\t"
    "s_waitcnt vmcnt(0)"
    : "=&v"(hf[0]), "=&v"(hf[1]), "=&v"(hf[2]), "=&v"(hf[3]),
      "=&v"(hf[4]), "=&v"(hf[5]), "=&v"(hf[6]), "=&v"(hf[7]),
      "=&v"(hf[8]), "=&v"(hf[9]), "=&v"(hf[10]), "=&v"(hf[11]),
      "=&v"(hf[12]), "=&v"(hf[13]), "=&v"(hf[14]), "=&v"(hf[15])
    : "v"(p)
    : "memory");
}

__device__ __forceinline__ u32 pkmax(u32 a, u32 b) {
  u32 r;
  asm("v_pk_max_u16 %0, %1, %2" : "=v"(r) : "v"(a), "v"(b));
  return r;
}

// ---------------- dtype sniff ----------------
__global__ void sniff_init(const void* W, u32* wsu) {
  int l = threadIdx.x;
  u32 v = ((const u32*)W)[l];
  u32 elo = (v >> 7) & 0xFFu;
  bool inband = (elo > 90u) && (elo < 130u);
  unsigned long long m = __ballot(inband);
  int cnt = __popcll(m);
  if (l == 0) wsu[0] = (cnt >= 32) ? 1u : 0u;
}

// -------- h gen0 = state (to bf16); gens 1..3 = sentinel --------
__global__ void h_init(const void* state, void* ws) {
  u32 flag = *(const u32*)ws;
  u16* h0 = (u16*)((char*)ws + WS_H_OFF);
  int i = blockIdx.x * blockDim.x + threadIdx.x;
  if (i < (int)H_ELEMS) {
    h0[i] = flag ? ((const u16*)state)[i] : f2b(((const float*)state)[i]);
    h0[i + H_ELEMS]     = 0xFFFFu;
    h0[i + 2 * H_ELEMS] = 0xFFFFu;
    h0[i + 3 * H_ELEMS] = 0xFFFFu;
  }
}

// stage 96 columns (3 gates x 32 units of this ug) of [512][1536] into LDS,
// transposed to [c][k] bf16 with XOR swizzle. 256 threads.
template<int MODE>
__device__ void stage_cols(const void* M, int ug, u16* lds) {
  int tid = threadIdx.x;
  #pragma unroll 4
  for (int it = 0; it < 192; ++it) {
    int idx = it * 256 + tid;           // 0..49151
    int k = idx / 96;
    int c = idx - k * 96;               // 0..95
    int col = (c >> 5) * UNITS + ug * 32 + (c & 31);
    float v = ldf<MODE>(M, (long)k * G3 + col);
    u32 byte = (u32)c * 1024u +
               ((((u32)k) * 2u) ^ (((u32)(c & 7)) << 4));
    *(u16*)((char*)lds + byte) = f2b(v);
  }
}

__device__ __forceinline__ short8 read_bfrag(const u16* lds, int c, int k) {
  u32 byte = (u32)c * 1024u +
             ((((u32)k) * 2u) ^ (((u32)(c & 7)) << 4));
  return *(const short8*)((const char*)lds + byte);
}

#define MFMA(a, b, c) __builtin_amdgcn_mfma_f32_16x16x32_bf16((a), (b), (c), 0, 0, 0)

template<int MODE>
__global__ __launch_bounds__(256, 1)
void gru_run(const void* __restrict__ xin, const int* __restrict__ dones,
             const int* __restrict__ stepin, const void* __restrict__ stin,
             const void* __restrict__ W,
             const void* __restrict__ U, const void* __restrict__ bias,
             void* __restrict__ out, void* __restrict__ ws)
{
  u32 flag = *(const u32*)ws;
  if (flag != (u32)MODE) return;

  __shared__ u16 wl[96 * 512];                 // 96 KB (U in prologue, then W)
  __shared__ float xmbuf[4][2][3][64][4];      // 24 KB x@W partials, 4-slot
  __shared__ int   dlds[16][NT];               // 8 KB dones prefetch
  __shared__ u32   sv[8];                      // 0-3: prod cnt; 4-7: cons cnt

  const int tid  = threadIdx.x;
  const int wv   = tid >> 6;           // 0,1 = h-consumer; 2,3 = x-producer
  const int l    = tid & 63;
  const int l15  = l & 15;
  const int ksub = (l >> 4) * 8;
  const int rsub = (l >> 4) * 4;

  const int bg = blockIdx.x & 15;
  const int ug = blockIdx.x >> 4;
  const int r0 = bg * ROWS_PER_BG;

  u16* hws = (u16*)((char*)ws + WS_H_OFF);

  if (tid < 8) sv[tid] = 0u;
  // dones prefetch: 16 rows x 128 t = 2048 ints, 8 per thread
  #pragma unroll
  for (int q = 0; q < 8; ++q) {
    int idx = q * 256 + tid;           // row = idx>>7, t = idx&127
    dlds[idx >> 7][idx & 127] = dones[(long)(r0 + (idx >> 7)) * NT + (idx & 127)];
  }

  // ---- prologue: U frags to consumer regs, W slice to LDS ----
  stage_cols<MODE>(U, ug, wl);
  __syncthreads();
  short8 ufz[16], ufrr[16], ufh[16];
  if (wv < 2) {
    #pragma unroll
    for (int kt = 0; kt < 16; ++kt) {
      int kb = kt * 32 + ksub;
      ufz[kt]  = read_bfrag(wl,      wv * 16 + l15, kb);
      ufrr[kt] = read_bfrag(wl, 32 + wv * 16 + l15, kb);
      ufh[kt]  = read_bfrag(wl, 64 + wv * 16 + l15, kb);
    }
  }
  __syncthreads();
  stage_cols<MODE>(W, ug, wl);
  __syncthreads();
  // ============ no __syncthreads below this line ============

  if (wv >= 2) {
    // ================= x-producer waves (run up to 4 steps ahead) =========
    const int xw = wv - 2;
    const int c0 = xw * 16 + l15, c1 = 32 + xw * 16 + l15, c2 = 64 + xw * 16 + l15;
    for (int t = 0; t < NT; ++t) {
      const int p = t & 3;
      const u32 u = (u32)(t >> 2);
      long xbase = ((long)(r0 + l15) * NT + t) * ND + ksub;
      short8 xf[16];
      #pragma unroll
      for (int kt = 0; kt < 16; ++kt) {
        if (MODE) {
          xf[kt] = *(const short8*)((const u16*)xin + xbase + kt * 32);
        } else {
          const float* q = (const float*)xin + xbase + kt * 32;
          f32x4 lo = *(const f32x4*)q;
          f32x4 hi = *(const f32x4*)(q + 4);
          short8 r;
          r[0] = (short)f2b(lo[0]); r[1] = (short)f2b(lo[1]);
          r[2] = (short)f2b(lo[2]); r[3] = (short)f2b(lo[3]);
          r[4] = (short)f2b(hi[0]); r[5] = (short)f2b(hi[1]);
          r[6] = (short)f2b(hi[2]); r[7] = (short)f2b(hi[3]);
          xf[kt] = r;
        }
      }
      // wait until consumers released this slot's previous use
      if (u > 0) {
        while (__hip_atomic_load(&sv[4 + p], __ATOMIC_ACQUIRE,
                                 __HIP_MEMORY_SCOPE_WORKGROUP) < 2u * u) {}
      }
      f32x4 az = {0,0,0,0}, ar = {0,0,0,0}, axh = {0,0,0,0};
      #pragma unroll
      for (int kt = 0; kt < 16; ++kt) {
        int kb = kt * 32 + ksub;
        az  = MFMA(xf[kt], read_bfrag(wl, c0, kb), az);
        ar  = MFMA(xf[kt], read_bfrag(wl, c1, kb), ar);
        axh = MFMA(xf[kt], read_bfrag(wl, c2, kb), axh);
      }
      *(f32x4*)&xmbuf[p][xw][0][l][0] = az;
      *(f32x4*)&xmbuf[p][xw][1][l][0] = ar;
      *(f32x4*)&xmbuf[p][xw][2][l][0] = axh;
      __hip_atomic_fetch_add(&sv[p], (l == 0) ? 1u : 0u, __ATOMIC_RELEASE,
                             __HIP_MEMORY_SCOPE_WORKGROUP);
    }
    return;
  }

  // ================= h-consumer waves =================
  const int w = wv;
  const int j = ug * 32 + w * 16 + l15;

  float bzs = ldf<MODE>(bias, j)        + ldf<MODE>(bias, G3 + j);
  float brs = ldf<MODE>(bias, 512 + j)  + ldf<MODE>(bias, G3 + 512 + j);
  float bxh = ldf<MODE>(bias, 1024 + j);
  float bhh = ldf<MODE>(bias, (long)G3 + 1024 + j);

  int sarr[4];
  float hprev[4];
  #pragma unroll
  for (int i = 0; i < 4; ++i) {
    int row = r0 + rsub + i;
    sarr[i]  = stepin[row];
    hprev[i] = ldf<MODE>(stin, (long)row * UNITS + j);
  }

  const long hbase = (long)(r0 + l15) * UNITS + ksub;

  for (int t = 0; t < NT; ++t) {
    const int p = t & 3;
    const u32 u = (u32)(t >> 2);

    // ---- speculative h load + in-register sentinel validation ----
    const u16* hg = hws + (long)(t & 3) * H_ELEMS;
    short8 hf[16];
    for (;;) {
      load_h16_coherent(hg + hbase, hf);
      u32 m0 = 0, m1 = 0, m2 = 0, m3 = 0;
      #pragma unroll
      for (int kt = 0; kt < 16; ++kt) {
        const u32* d = (const u32*)&hf[kt];
        m0 = pkmax(m0, d[0]); m1 = pkmax(m1, d[1]);
        m2 = pkmax(m2, d[2]); m3 = pkmax(m3, d[3]);
      }
      u32 m = pkmax(pkmax(m0, m1), pkmax(m2, m3));
      bool ok = ((m & 0xFFFFu) != 0xFFFFu) && ((m >> 16) != 0xFFFFu);
      if (__all(ok)) break;
    }

    // ---- h@U MFMAs ----
    f32x4 az = {0,0,0,0}, ar = {0,0,0,0}, ahh = {0,0,0,0};
    #pragma unroll
    for (int kt = 0; kt < 16; ++kt) {
      az  = MFMA(hf[kt], ufz[kt],  az);
      ar  = MFMA(hf[kt], ufrr[kt], ar);
      ahh = MFMA(hf[kt], ufh[kt],  ahh);
    }

    // ---- pick up x@W partials (normally ready well ahead) ----
    while (__hip_atomic_load(&sv[p], __ATOMIC_ACQUIRE,
                             __HIP_MEMORY_SCOPE_WORKGROUP) < 2u * (u + 1u)) {}
    f32x4 axh = *(const f32x4*)&xmbuf[p][w][2][l][0];
    {
      f32x4 xz = *(const f32x4*)&xmbuf[p][w][0][l][0];
      f32x4 xr = *(const f32x4*)&xmbuf[p][w][1][l][0];
      az[0] += xz[0]; az[1] += xz[1]; az[2] += xz[2]; az[3] += xz[3];
      ar[0] += xr[0]; ar[1] += xr[1]; ar[2] += xr[2]; ar[3] += xr[3];
    }
    __hip_atomic_fetch_add(&sv[4 + p], (l == 0) ? 1u : 0u, __ATOMIC_RELEASE,
                           __HIP_MEMORY_SCOPE_WORKGROUP);

    // ---- gates + reset; h stores ARE the publish ----
    u16* hn = hws + (long)((t + 1) & 3) * H_ELEMS;
    float hnew_r[4];
    #pragma unroll
    for (int i = 0; i < 4; ++i) {
      int row = r0 + rsub + i;
      float z  = 1.0f / (1.0f + __expf(-(az[i] + bzs)));
      float rr = 1.0f / (1.0f + __expf(-(ar[i] + brs)));
      float tx = axh[i] + bxh + rr * (ahh[i] + bhh);
      tx = fminf(15.0f, fmaxf(-15.0f, tx));
      float e  = __expf(2.0f * tx);
      float hcand = (e - 1.0f) / (e + 1.0f);
      float hnew = z * hprev[i] + (1.0f - z) * hcand;
      hnew_r[i] = hnew;

      int sn = sarr[i] + 1;
      bool reset = (dlds[rsub + i][t] == 1) || ((sn & 15) == 0);
      float hkeep = reset ? 0.0f : hnew;
      sarr[i] = reset ? 0 : sn;
      hprev[i] = hkeep;
      if (t < NT - 1)
        store_h_coherent(hn + (long)row * UNITS + j, f2b(hkeep));
    }

    // ---- designated invalidator: re-sentinel gen (t-1)&3 for its reuse ----
    // Safe: our validate(t) success implies every sibling finished reading
    // gen (t-1)&3. These stores drain via our next validate's vmcnt(0),
    // causally before that buffer's next writer (step t+3).
    if (ug == 0 && t >= 1 && t < NT - 1) {
      u16* inv = hws + (long)((t - 1) & 3) * H_ELEMS;
      int irow = r0 + w * 8 + (l >> 3);
      long ib = (long)irow * UNITS + (l & 7) * 8;
      #pragma unroll
      for (int q = 0; q < 8; ++q)
        store_sent16(inv + ib + q * 64);
    }

    // ---- deferred outputs (not on the inter-block critical path) ----
    #pragma unroll
    for (int i = 0; i < 4; ++i) {
      int row = r0 + rsub + i;
      long qo = ((long)row * NT + t) * UNITS + j;
      if (MODE) ((u16*)out)[qo] = f2b(hnew_r[i]);
      else      ((float*)out)[qo] = hnew_r[i];

      if (t == NT - 1) {
        long so = STATE_OFF + (long)row * UNITS + j;
        if (MODE) ((u16*)out)[so] = f2b(hprev[i]);
        else      ((float*)out)[so] = hprev[i];
        if (w == 0 && l15 == 0 && ug == 0) {
          long po = STEP_OFF + row;
          float sval = (float)sarr[i];
          if (MODE) ((u16*)out)[po] = f2b(sval);
          else      ((float*)out)[po] = sval;
        }
      }
    }
  }
}

extern "C" void kernel_launch(void* const* d_in, const int* in_sizes, int n_in,
                              void* d_out, int out_size, void* d_ws, size_t ws_size,
                              hipStream_t stream) {
  const void* xin    = d_in[0];
  const int*  dones  = (const int*)d_in[1];
  const void* stin   = d_in[2];
  const int*  stepin = (const int*)d_in[3];
  const void* W      = d_in[4];
  const void* U      = d_in[5];
  const void* bias   = d_in[6];

  sniff_init<<<1, 64, 0, stream>>>(W, (u32*)d_ws);
  h_init<<<256, 512, 0, stream>>>(stin, d_ws);
  gru_run<0><<<256, 256, 0, stream>>>(xin, dones, stepin, stin, W, U, bias, d_out, d_ws);
  gru_run<1><<<256, 256, 0, stream>>>(xin, dones, stepin, stin, W, U, bias, d_out, d_ws);
}

// Round 7
// 954.901 us; speedup vs baseline: 1.2004x; 1.2004x over previous
//
#include <hip/hip_runtime.h>
#include <cstdint>

#define UNITS 512
#define NB 256
#define NT 128
#define ND 512
#define G3 1536

#define SEQ_ELEMS (16777216L)              // 256*128*512
#define STATE_OFF (SEQ_ELEMS)
#define STEP_OFF  (SEQ_ELEMS + 131072L)

#define BGS 16
#define ROWS_PER_BG 16

#define WS_FLAG_OFF 4096                   // 16 bg x 32 waves x 64B = 32KB
#define WS_H_OFF    65536
#define H_ELEMS     131072L                // 256*512 per generation; 2 gens

typedef unsigned short u16;
typedef short short8 __attribute__((ext_vector_type(8)));
typedef float f32x4 __attribute__((ext_vector_type(4)));
typedef unsigned int u32;

__device__ __forceinline__ u16 f2b(float f) {
  u32 x = __float_as_uint(f);
  u32 r = (x + 0x7FFFu + ((x >> 16) & 1u)) >> 16;
  return (u16)r;
}
__device__ __forceinline__ float b2f(u16 u) {
  return __uint_as_float(((u32)u) << 16);
}

template<int MODE>
__device__ __forceinline__ float ldf(const void* p, long idx) {
  if (MODE) return b2f(((const u16*)p)[idx]);
  else      return ((const float*)p)[idx];
}

// coherent MALL read (bypass L1/L2)
__device__ __forceinline__ u32 load_flag_coherent(const u32* p) {
  u32 v;
  asm volatile("global_load_dword %0, %1, off sc0 sc1\n\t"
               "s_waitcnt vmcnt(0)"
               : "=v"(v) : "v"(p) : "memory");
  return v;
}

// 16 pipelined 16B coherent loads + single drain (gfx950: offset BEFORE sc flags)
__device__ __forceinline__ void load_h16_coherent(const u16* p, short8 hf[16]) {
  asm volatile(
    "global_load_dwordx4 %0, %16, off sc0 sc1\n\t"
    "global_load_dwordx4 %1, %16, off offset:64 sc0 sc1\n\t"
    "global_load_dwordx4 %2, %16, off offset:128 sc0 sc1\n\t"
    "global_load_dwordx4 %3, %16, off offset:192 sc0 sc1\n\t"
    "global_load_dwordx4 %4, %16, off offset:256 sc0 sc1\n\t"
    "global_load_dwordx4 %5, %16, off offset:320 sc0 sc1\n\t"
    "global_load_dwordx4 %6, %16, off offset:384 sc0 sc1\n\t"
    "global_load_dwordx4 %7, %16, off offset:448 sc0 sc1\n\t"
    "global_load_dwordx4 %8, %16, off offset:512 sc0 sc1\n\t"
    "global_load_dwordx4 %9, %16, off offset:576 sc0 sc1\n\t"
    "global_load_dwordx4 %10, %16, off offset:640 sc0 sc1\n\t"
    "global_load_dwordx4 %11, %16, off offset:704 sc0 sc1\n\t"
    "global_load_dwordx4 %12, %16, off offset:768 sc0 sc1\n\t"
    "global_load_dwordx4 %13, %16, off offset:832 sc0 sc1\n\t"
    "global_load_dwordx4 %14, %16, off offset:896 sc0 sc1\n\t"
    "global_load_dwordx4 %15, %16, off offset:960 sc0 sc1\n\t"
    "s_waitcnt vmcnt(0)"
    : "=&v"(hf[0]), "=&v"(hf[1]), "=&v"(hf[2]), "=&v"(hf[3]),
      "=&v"(hf[4]), "=&v"(hf[5]), "=&v"(hf[6]), "=&v"(hf[7]),
      "=&v"(hf[8]), "=&v"(hf[9]), "=&v"(hf[10]), "=&v"(hf[11]),
      "=&v"(hf[12]), "=&v"(hf[13]), "=&v"(hf[14]), "=&v"(hf[15])
    : "v"(p)
    : "memory");
}

// ---------------- dtype sniff ----------------
__global__ void sniff_init(const void* W, u32* wsu) {
  int l = threadIdx.x;
  u32 v = ((const u32*)W)[l];
  u32 elo = (v >> 7) & 0xFFu;
  bool inband = (elo > 90u) && (elo < 130u);
  unsigned long long m = __ballot(inband);
  int cnt = __popcll(m);
  if (l == 0) wsu[0] = (cnt >= 32) ? 1u : 0u;
}

// -------- h gen0 = state (to bf16); zero flag lines --------
__global__ void h_init(const void* state, void* ws) {
  u32 flag = *(const u32*)ws;
  u16* h0 = (u16*)((char*)ws + WS_H_OFF);
  int i = blockIdx.x * blockDim.x + threadIdx.x;
  if (i < (int)H_ELEMS) {
    h0[i] = flag ? ((const u16*)state)[i] : f2b(((const float*)state)[i]);
  }
  if (i < 8192) {   // 32KB of flag lines
    ((u32*)((char*)ws + WS_FLAG_OFF))[i] = 0u;
  }
}

// stage 96 columns (3 gates x 32 units of this ug) of [512][1536] into LDS,
// transposed to [c][k] bf16 with XOR swizzle. 256 threads.
template<int MODE>
__device__ void stage_cols(const void* M, int ug, u16* lds) {
  int tid = threadIdx.x;
  #pragma unroll 4
  for (int it = 0; it < 192; ++it) {
    int idx = it * 256 + tid;           // 0..49151
    int k = idx / 96;
    int c = idx - k * 96;               // 0..95
    int col = (c >> 5) * UNITS + ug * 32 + (c & 31);
    float v = ldf<MODE>(M, (long)k * G3 + col);
    u32 byte = (u32)c * 1024u +
               ((((u32)k) * 2u) ^ (((u32)(c & 7)) << 4));
    *(u16*)((char*)lds + byte) = f2b(v);
  }
}

__device__ __forceinline__ short8 read_bfrag(const u16* lds, int c, int k) {
  u32 byte = (u32)c * 1024u +
             ((((u32)k) * 2u) ^ (((u32)(c & 7)) << 4));
  return *(const short8*)((const char*)lds + byte);
}

#define MFMA(a, b, c) __builtin_amdgcn_mfma_f32_16x16x32_bf16((a), (b), (c), 0, 0, 0)

template<int MODE>
__global__ __launch_bounds__(256, 1)
void gru_run(const void* __restrict__ xin, const int* __restrict__ dones,
             const int* __restrict__ stepin, const void* __restrict__ stin,
             const void* __restrict__ W,
             const void* __restrict__ U, const void* __restrict__ bias,
             void* __restrict__ out, void* __restrict__ ws)
{
  u32 flag = *(const u32*)ws;
  if (flag != (u32)MODE) return;

  __shared__ u16 wl[96 * 512];                 // 96 KB (U in prologue, then W)
  __shared__ float xmbuf[4][2][3][64][4];      // 24 KB x@W partials, 4-slot
  __shared__ int   dlds[16][NT];               // 8 KB dones prefetch
  __shared__ u32   sv[8];                      // 0-3: prod cnt; 4-7: cons cnt

  const int tid  = threadIdx.x;
  const int wv   = tid >> 6;           // 0,1 = h-consumer; 2,3 = x-producer
  const int l    = tid & 63;
  const int l15  = l & 15;
  const int ksub = (l >> 4) * 8;
  const int rsub = (l >> 4) * 4;

  const int bg = blockIdx.x & 15;
  const int ug = blockIdx.x >> 4;
  const int r0 = bg * ROWS_PER_BG;

  u32* flags = (u32*)((char*)ws + WS_FLAG_OFF);  // (bg*32 + ug*2 + w)*16 dwords
  u16* hws = (u16*)((char*)ws + WS_H_OFF);

  if (tid < 8) sv[tid] = 0u;
  // dones prefetch: 16 rows x 128 t = 2048 ints, 8 per thread
  #pragma unroll
  for (int q = 0; q < 8; ++q) {
    int idx = q * 256 + tid;           // row = idx>>7, t = idx&127
    dlds[idx >> 7][idx & 127] = dones[(long)(r0 + (idx >> 7)) * NT + (idx & 127)];
  }

  // ---- prologue: U frags to consumer regs, W slice to LDS ----
  stage_cols<MODE>(U, ug, wl);
  __syncthreads();
  short8 ufz[16], ufrr[16], ufh[16];
  if (wv < 2) {
    #pragma unroll
    for (int kt = 0; kt < 16; ++kt) {
      int kb = kt * 32 + ksub;
      ufz[kt]  = read_bfrag(wl,      wv * 16 + l15, kb);
      ufrr[kt] = read_bfrag(wl, 32 + wv * 16 + l15, kb);
      ufh[kt]  = read_bfrag(wl, 64 + wv * 16 + l15, kb);
    }
  }
  __syncthreads();
  stage_cols<MODE>(W, ug, wl);
  __syncthreads();
  // ============ no __syncthreads below this line ============

  if (wv >= 2) {
    // ================= x-producer waves (up to 4 steps ahead) =========
    const int xw = wv - 2;
    const int c0 = xw * 16 + l15, c1 = 32 + xw * 16 + l15, c2 = 64 + xw * 16 + l15;
    for (int t = 0; t < NT; ++t) {
      const int p = t & 3;
      const u32 u = (u32)(t >> 2);
      long xbase = ((long)(r0 + l15) * NT + t) * ND + ksub;
      short8 xf[16];
      #pragma unroll
      for (int kt = 0; kt < 16; ++kt) {
        if (MODE) {
          xf[kt] = *(const short8*)((const u16*)xin + xbase + kt * 32);
        } else {
          const float* q = (const float*)xin + xbase + kt * 32;
          f32x4 lo = *(const f32x4*)q;
          f32x4 hi = *(const f32x4*)(q + 4);
          short8 r;
          r[0] = (short)f2b(lo[0]); r[1] = (short)f2b(lo[1]);
          r[2] = (short)f2b(lo[2]); r[3] = (short)f2b(lo[3]);
          r[4] = (short)f2b(hi[0]); r[5] = (short)f2b(hi[1]);
          r[6] = (short)f2b(hi[2]); r[7] = (short)f2b(hi[3]);
          xf[kt] = r;
        }
      }
      if (u > 0) {
        while (__hip_atomic_load(&sv[4 + p], __ATOMIC_ACQUIRE,
                                 __HIP_MEMORY_SCOPE_WORKGROUP) < 2u * u) {}
      }
      f32x4 az = {0,0,0,0}, ar = {0,0,0,0}, axh = {0,0,0,0};
      #pragma unroll
      for (int kt = 0; kt < 16; ++kt) {
        int kb = kt * 32 + ksub;
        az  = MFMA(xf[kt], read_bfrag(wl, c0, kb), az);
        ar  = MFMA(xf[kt], read_bfrag(wl, c1, kb), ar);
        axh = MFMA(xf[kt], read_bfrag(wl, c2, kb), axh);
      }
      *(f32x4*)&xmbuf[p][xw][0][l][0] = az;
      *(f32x4*)&xmbuf[p][xw][1][l][0] = ar;
      *(f32x4*)&xmbuf[p][xw][2][l][0] = axh;
      __hip_atomic_fetch_add(&sv[p], (l == 0) ? 1u : 0u, __ATOMIC_RELEASE,
                             __HIP_MEMORY_SCOPE_WORKGROUP);
    }
    return;
  }

  // ================= h-consumer waves =================
  const int w = wv;
  const int j = ug * 32 + w * 16 + l15;
  u32* myflag = flags + (long)(bg * 32 + ug * 2 + w) * 16;

  float bzs = ldf<MODE>(bias, j)        + ldf<MODE>(bias, G3 + j);
  float brs = ldf<MODE>(bias, 512 + j)  + ldf<MODE>(bias, G3 + 512 + j);
  float bxh = ldf<MODE>(bias, 1024 + j);
  float bhh = ldf<MODE>(bias, (long)G3 + 1024 + j);

  int sarr[4];
  float hprev[4];
  #pragma unroll
  for (int i = 0; i < 4; ++i) {
    int row = r0 + rsub + i;
    sarr[i]  = stepin[row];
    hprev[i] = ldf<MODE>(stin, (long)row * UNITS + j);
  }

  const long hbase = (long)(r0 + l15) * UNITS + ksub;

  for (int t = 0; t < NT; ++t) {
    const int p = t & 3;
    const u32 u = (u32)(t >> 2);

    // ---- wait: all 32 sibling waves (16 blocks) published step t-1 ----
    if (t > 0) {
      const u32* fp_ = flags + (long)(bg * 32 + l) * 16;
      bool pred;
      do {
        u32 fv = (l < 32) ? load_flag_coherent(fp_) : (u32)t;
        pred = (fv >= (u32)t);
      } while (!__all(pred));
    }

    // ---- h loads (coherent MALL reads, drained inside asm) ----
    const u16* hg = hws + (long)(t & 1) * H_ELEMS;
    short8 hf[16];
    load_h16_coherent(hg + hbase, hf);

    // ---- h@U MFMAs ----
    f32x4 az = {0,0,0,0}, ar = {0,0,0,0}, ahh = {0,0,0,0};
    #pragma unroll
    for (int kt = 0; kt < 16; ++kt) {
      az  = MFMA(hf[kt], ufz[kt],  az);
      ar  = MFMA(hf[kt], ufrr[kt], ar);
      ahh = MFMA(hf[kt], ufh[kt],  ahh);
    }

    // ---- pick up x@W partials (normally ready ahead) ----
    while (__hip_atomic_load(&sv[p], __ATOMIC_ACQUIRE,
                             __HIP_MEMORY_SCOPE_WORKGROUP) < 2u * (u + 1u)) {}
    f32x4 axh = *(const f32x4*)&xmbuf[p][w][2][l][0];
    {
      f32x4 xz = *(const f32x4*)&xmbuf[p][w][0][l][0];
      f32x4 xr = *(const f32x4*)&xmbuf[p][w][1][l][0];
      az[0] += xz[0]; az[1] += xz[1]; az[2] += xz[2]; az[3] += xz[3];
      ar[0] += xr[0]; ar[1] += xr[1]; ar[2] += xr[2]; ar[3] += xr[3];
    }
    __hip_atomic_fetch_add(&sv[4 + p], (l == 0) ? 1u : 0u, __ATOMIC_RELEASE,
                           __HIP_MEMORY_SCOPE_WORKGROUP);

    // ---- gates + reset ----
    u16* hn = hws + (long)((t + 1) & 1) * H_ELEMS;
    float hnew_r[4];
    u32 hv[4];
    #pragma unroll
    for (int i = 0; i < 4; ++i) {
      float z  = 1.0f / (1.0f + __expf(-(az[i] + bzs)));
      float rr = 1.0f / (1.0f + __expf(-(ar[i] + brs)));
      float tx = axh[i] + bxh + rr * (ahh[i] + bhh);
      tx = fminf(15.0f, fmaxf(-15.0f, tx));
      float e  = __expf(2.0f * tx);
      float hcand = (e - 1.0f) / (e + 1.0f);
      float hnew = z * hprev[i] + (1.0f - z) * hcand;
      hnew_r[i] = hnew;

      int sn = sarr[i] + 1;
      bool reset = (dlds[rsub + i][t] == 1) || ((sn & 15) == 0);
      float hkeep = reset ? 0.0f : hnew;
      sarr[i] = reset ? 0 : sn;
      hprev[i] = hkeep;
      hv[i] = (u32)f2b(hkeep);
    }

    // ---- publish h via dword atomicExch (executes at MALL, no HBM
    // ---- write-through); then drain (MALL ack) and publish wave flag ----
    if (t < NT - 1) {
      #pragma unroll
      for (int i = 0; i < 4; ++i) {
        u32 other = __shfl_xor(hv[i], 1);
        u32 dw = (l & 1) ? ((hv[i] << 16) | other) : (hv[i] | (other << 16));
        // even lane stores rows rsub+0,1; odd lane rows rsub+2,3
        if ((i < 2) == ((l & 1) == 0)) {
          int row = r0 + rsub + i;
          u32* ap = (u32*)(hn + (long)row * UNITS + (j & ~1));
          atomicExch(ap, dw);
        }
      }
      asm volatile("s_waitcnt vmcnt(0)" ::: "memory");
      if (l == 0) atomicExch(myflag, (u32)(t + 1));
    }

    // ---- deferred outputs (off the inter-block critical path) ----
    #pragma unroll
    for (int i = 0; i < 4; ++i) {
      int row = r0 + rsub + i;
      long qo = ((long)row * NT + t) * UNITS + j;
      if (MODE) ((u16*)out)[qo] = f2b(hnew_r[i]);
      else      ((float*)out)[qo] = hnew_r[i];

      if (t == NT - 1) {
        long so = STATE_OFF + (long)row * UNITS + j;
        if (MODE) ((u16*)out)[so] = f2b(hprev[i]);
        else      ((float*)out)[so] = hprev[i];
        if (w == 0 && l15 == 0 && ug == 0) {
          long po = STEP_OFF + row;
          float sval = (float)sarr[i];
          if (MODE) ((u16*)out)[po] = f2b(sval);
          else      ((float*)out)[po] = sval;
        }
      }
    }
  }
}

extern "C" void kernel_launch(void* const* d_in, const int* in_sizes, int n_in,
                              void* d_out, int out_size, void* d_ws, size_t ws_size,
                              hipStream_t stream) {
  const void* xin    = d_in[0];
  const int*  dones  = (const int*)d_in[1];
  const void* stin   = d_in[2];
  const int*  stepin = (const int*)d_in[3];
  const void* W      = d_in[4];
  const void* U      = d_in[5];
  const void* bias   = d_in[6];

  sniff_init<<<1, 64, 0, stream>>>(W, (u32*)d_ws);
  h_init<<<256, 512, 0, stream>>>(stin, d_ws);
  gru_run<0><<<256, 256, 0, stream>>>(xin, dones, stepin, stin, W, U, bias, d_out, d_ws);
  gru_run<1><<<256, 256, 0, stream>>>(xin, dones, stepin, stin, W, U, bias, d_out, d_ws);
}

// Round 11
// 838.758 us; speedup vs baseline: 1.3666x; 1.1385x over previous
//
#include <hip/hip_runtime.h>
#include <cstdint>

#define UNITS 512
#define NB 256
#define NT 128
#define ND 512
#define G3 1536

#define SEQ_ELEMS (16777216L)              // 256*128*512
#define STATE_OFF (SEQ_ELEMS)
#define STEP_OFF  (SEQ_ELEMS + 131072L)

#define ROWS_PER_BG 16

#define WS_FLAG_OFF 4096                   // 16 bg x 32 waves x 64B = 32KB
#define WS_H_OFF    65536
#define H_ELEMS     131072L                // 256*512 u16 per generation; 2 gens

typedef unsigned short u16;
typedef short short8 __attribute__((ext_vector_type(8)));
typedef float f32x4 __attribute__((ext_vector_type(4)));
typedef unsigned int u32;

__device__ __forceinline__ u16 f2b(float f) {
  u32 x = __float_as_uint(f);
  u32 r = (x + 0x7FFFu + ((x >> 16) & 1u)) >> 16;
  return (u16)r;
}
__device__ __forceinline__ float b2f(u16 u) {
  return __uint_as_float(((u32)u) << 16);
}

template<int MODE>
__device__ __forceinline__ float ldf(const void* p, long idx) {
  if (MODE) return b2f(((const u16*)p)[idx]);
  else      return ((const float*)p)[idx];
}

// ---- coherent (MALL) primitives: per-access sc0/sc1, no L2 flushes ----
__device__ __forceinline__ void store_h_coherent(const u16* p, u16 v) {
  u32 vv = v;
  asm volatile("global_store_short %0, %1, off sc0 sc1"
               :: "v"(p), "v"(vv) : "memory");
}
__device__ __forceinline__ void st_flag(const u32* p, u32 v) {
  asm volatile("global_store_dword %0, %1, off sc0 sc1"
               :: "v"(p), "v"(v) : "memory");
}
__device__ __forceinline__ u32 load_flag_coherent(const u32* p) {
  u32 v;
  asm volatile("global_load_dword %0, %1, off sc0 sc1\n\t"
               "s_waitcnt vmcnt(0)"
               : "=v"(v) : "v"(p) : "memory");
  return v;
}

// 16 pipelined 16B coherent loads + single drain (gfx950: offset BEFORE sc flags)
__device__ __forceinline__ void load_h16_coherent(const u16* p, short8 hf[16]) {
  asm volatile(
    "global_load_dwordx4 %0, %16, off sc0 sc1\n\t"
    "global_load_dwordx4 %1, %16, off offset:64 sc0 sc1\n\t"
    "global_load_dwordx4 %2, %16, off offset:128 sc0 sc1\n\t"
    "global_load_dwordx4 %3, %16, off offset:192 sc0 sc1\n\t"
    "global_load_dwordx4 %4, %16, off offset:256 sc0 sc1\n\t"
    "global_load_dwordx4 %5, %16, off offset:320 sc0 sc1\n\t"
    "global_load_dwordx4 %6, %16, off offset:384 sc0 sc1\n\t"
    "global_load_dwordx4 %7, %16, off offset:448 sc0 sc1\n\t"
    "global_load_dwordx4 %8, %16, off offset:512 sc0 sc1\n\t"
    "global_load_dwordx4 %9, %16, off offset:576 sc0 sc1\n\t"
    "global_load_dwordx4 %10, %16, off offset:640 sc0 sc1\n\t"
    "global_load_dwordx4 %11, %16, off offset:704 sc0 sc1\n\t"
    "global_load_dwordx4 %12, %16, off offset:768 sc0 sc1\n\t"
    "global_load_dwordx4 %13, %16, off offset:832 sc0 sc1\n\t"
    "global_load_dwordx4 %14, %16, off offset:896 sc0 sc1\n\t"
    "global_load_dwordx4 %15, %16, off offset:960 sc0 sc1\n\t"
    "s_waitcnt vmcnt(0)"
    : "=&v"(hf[0]), "=&v"(hf[1]), "=&v"(hf[2]), "=&v"(hf[3]),
      "=&v"(hf[4]), "=&v"(hf[5]), "=&v"(hf[6]), "=&v"(hf[7]),
      "=&v"(hf[8]), "=&v"(hf[9]), "=&v"(hf[10]), "=&v"(hf[11]),
      "=&v"(hf[12]), "=&v"(hf[13]), "=&v"(hf[14]), "=&v"(hf[15])
    : "v"(p)
    : "memory");
}

// ---------------- dtype sniff ----------------
__global__ void sniff_init(const void* W, u32* wsu) {
  int l = threadIdx.x;
  u32 v = ((const u32*)W)[l];
  u32 elo = (v >> 7) & 0xFFu;
  bool inband = (elo > 90u) && (elo < 130u);
  unsigned long long m = __ballot(inband);
  int cnt = __popcll(m);
  if (l == 0) wsu[0] = (cnt >= 32) ? 1u : 0u;
}

// -------- h gen0 = state (to bf16); zero flag lines --------
__global__ void h_init(const void* state, void* ws) {
  u32 flag = *(const u32*)ws;
  u16* h0 = (u16*)((char*)ws + WS_H_OFF);
  int i = blockIdx.x * blockDim.x + threadIdx.x;
  if (i < (int)H_ELEMS) {
    h0[i] = flag ? ((const u16*)state)[i] : f2b(((const float*)state)[i]);
  }
  if (i < 8192) {   // 32KB of flag lines
    ((u32*)((char*)ws + WS_FLAG_OFF))[i] = 0u;
  }
}

// stage 96 columns (3 gates x 32 units of this ug) of [512][1536] into LDS,
// transposed to [c][k] bf16 with XOR swizzle. 256 threads.
template<int MODE>
__device__ void stage_cols(const void* M, int ug, u16* lds) {
  int tid = threadIdx.x;
  #pragma unroll 4
  for (int it = 0; it < 192; ++it) {
    int idx = it * 256 + tid;           // 0..49151
    int k = idx / 96;
    int c = idx - k * 96;               // 0..95
    int col = (c >> 5) * UNITS + ug * 32 + (c & 31);
    float v = ldf<MODE>(M, (long)k * G3 + col);
    u32 byte = (u32)c * 1024u +
               ((((u32)k) * 2u) ^ (((u32)(c & 7)) << 4));
    *(u16*)((char*)lds + byte) = f2b(v);
  }
}

__device__ __forceinline__ short8 read_bfrag(const u16* lds, int c, int k) {
  u32 byte = (u32)c * 1024u +
             ((((u32)k) * 2u) ^ (((u32)(c & 7)) << 4));
  return *(const short8*)((const char*)lds + byte);
}

#define MFMA(a, b, c) __builtin_amdgcn_mfma_f32_16x16x32_bf16((a), (b), (c), 0, 0, 0)

template<int MODE>
__global__ __launch_bounds__(256, 1)
void gru_run(const void* __restrict__ xin, const int* __restrict__ dones,
             const int* __restrict__ stepin, const void* __restrict__ stin,
             const void* __restrict__ W,
             const void* __restrict__ U, const void* __restrict__ bias,
             void* __restrict__ out, void* __restrict__ ws)
{
  u32 flag = *(const u32*)ws;
  if (flag != (u32)MODE) return;

  __shared__ u16  wl[96 * 512];                // 96 KB (U in prologue, then W)
  __shared__ float xmbuf[4][2][3][64][4];      // 24 KB x@W partials, 4-slot
  __shared__ int   dlds[16][NT];               // 8 KB dones prefetch
  __shared__ u32   sv[8];                      // 0-3 prod cnt; 4-7 cons cnt

  const int tid  = threadIdx.x;
  const int wv   = tid >> 6;           // 0,1 = h-consumer; 2,3 = x-producer
  const int l    = tid & 63;
  const int l15  = l & 15;
  const int ksub = (l >> 4) * 8;
  const int rsub = (l >> 4) * 4;

  const int bg = blockIdx.x & 15;
  const int ug = blockIdx.x >> 4;
  const int r0 = bg * ROWS_PER_BG;

  u32* flags = (u32*)((char*)ws + WS_FLAG_OFF);  // (bg*32 + ug*2 + w)*16 dwords
  u16* hws = (u16*)((char*)ws + WS_H_OFF);

  if (tid < 8) sv[tid] = 0u;
  // dones prefetch: 16 rows x 128 t = 2048 ints, 8 per thread
  #pragma unroll
  for (int q = 0; q < 8; ++q) {
    int idx = q * 256 + tid;           // row = idx>>7, t = idx&127
    dlds[idx >> 7][idx & 127] = dones[(long)(r0 + (idx >> 7)) * NT + (idx & 127)];
  }

  // ---- prologue: U frags to consumer regs, W slice to LDS ----
  stage_cols<MODE>(U, ug, wl);
  __syncthreads();
  short8 ufz[16], ufrr[16], ufh[16];
  if (wv < 2) {
    #pragma unroll
    for (int kt = 0; kt < 16; ++kt) {
      int kb = kt * 32 + ksub;
      ufz[kt]  = read_bfrag(wl,      wv * 16 + l15, kb);
      ufrr[kt] = read_bfrag(wl, 32 + wv * 16 + l15, kb);
      ufh[kt]  = read_bfrag(wl, 64 + wv * 16 + l15, kb);
    }
  }
  __syncthreads();
  stage_cols<MODE>(W, ug, wl);
  __syncthreads();
  // ============ no __syncthreads below this line ============

  if (wv >= 2) {
    // ================= x-producer waves (up to 4 steps ahead) =========
    const int xw = wv - 2;
    const int c0 = xw * 16 + l15, c1 = 32 + xw * 16 + l15, c2 = 64 + xw * 16 + l15;
    for (int t = 0; t < NT; ++t) {
      const int p = t & 3;
      const u32 u = (u32)(t >> 2);
      long xbase = ((long)(r0 + l15) * NT + t) * ND + ksub;
      short8 xf[16];
      #pragma unroll
      for (int kt = 0; kt < 16; ++kt) {
        if (MODE) {
          xf[kt] = *(const short8*)((const u16*)xin + xbase + kt * 32);
        } else {
          const float* q = (const float*)xin + xbase + kt * 32;
          f32x4 lo = *(const f32x4*)q;
          f32x4 hi = *(const f32x4*)(q + 4);
          short8 r;
          r[0] = (short)f2b(lo[0]); r[1] = (short)f2b(lo[1]);
          r[2] = (short)f2b(lo[2]); r[3] = (short)f2b(lo[3]);
          r[4] = (short)f2b(hi[0]); r[5] = (short)f2b(hi[1]);
          r[6] = (short)f2b(hi[2]); r[7] = (short)f2b(hi[3]);
          xf[kt] = r;
        }
      }
      if (u > 0) {
        while (__hip_atomic_load(&sv[4 + p], __ATOMIC_ACQUIRE,
                                 __HIP_MEMORY_SCOPE_WORKGROUP) < 2u * u) {}
      }
      f32x4 az = {0,0,0,0}, ar = {0,0,0,0}, axh = {0,0,0,0};
      #pragma unroll
      for (int kt = 0; kt < 16; ++kt) {
        int kb = kt * 32 + ksub;
        az  = MFMA(xf[kt], read_bfrag(wl, c0, kb), az);
        ar  = MFMA(xf[kt], read_bfrag(wl, c1, kb), ar);
        axh = MFMA(xf[kt], read_bfrag(wl, c2, kb), axh);
      }
      *(f32x4*)&xmbuf[p][xw][0][l][0] = az;
      *(f32x4*)&xmbuf[p][xw][1][l][0] = ar;
      *(f32x4*)&xmbuf[p][xw][2][l][0] = axh;
      __hip_atomic_fetch_add(&sv[p], (l == 0) ? 1u : 0u, __ATOMIC_RELEASE,
                             __HIP_MEMORY_SCOPE_WORKGROUP);
    }
    return;
  }

  // ================= h-consumer waves =================
  const int w = wv;
  const int j = ug * 32 + w * 16 + l15;
  u32* myflag = flags + (long)(bg * 32 + ug * 2 + w) * 16;

  float bzs = ldf<MODE>(bias, j)        + ldf<MODE>(bias, G3 + j);
  float brs = ldf<MODE>(bias, 512 + j)  + ldf<MODE>(bias, G3 + 512 + j);
  float bxh = ldf<MODE>(bias, 1024 + j);
  float bhh = ldf<MODE>(bias, (long)G3 + 1024 + j);

  int sarr[4];
  float hprev[4];
  #pragma unroll
  for (int i = 0; i < 4; ++i) {
    int row = r0 + rsub + i;
    sarr[i]  = stepin[row];
    hprev[i] = ldf<MODE>(stin, (long)row * UNITS + j);
  }

  const long hbase = (long)(r0 + l15) * UNITS + ksub;

  for (int t = 0; t < NT; ++t) {
    const int p = t & 3;
    const u32 u = (u32)(t >> 2);

    // ---- wait: all 32 sibling consumer waves published step t-1 ----
    if (t > 0) {
      const u32* fp_ = flags + (long)(bg * 32 + l) * 16;
      bool pred;
      do {
        u32 fv = (l < 32) ? load_flag_coherent(fp_) : (u32)t;
        pred = (fv >= (u32)t);
      } while (!__all(pred));
    }

    // ---- h loads (coherent MALL reads, drained inside asm) ----
    const u16* hb = hws + (long)(t & 1) * H_ELEMS;
    short8 hf[16];
    load_h16_coherent(hb + hbase, hf);

    // ---- h@U MFMAs ----
    f32x4 az = {0,0,0,0}, ar = {0,0,0,0}, ahh = {0,0,0,0};
    #pragma unroll
    for (int kt = 0; kt < 16; ++kt) {
      az  = MFMA(hf[kt], ufz[kt],  az);
      ar  = MFMA(hf[kt], ufrr[kt], ar);
      ahh = MFMA(hf[kt], ufh[kt],  ahh);
    }

    // ---- pick up x@W partials (normally ready ahead) ----
    while (__hip_atomic_load(&sv[p], __ATOMIC_ACQUIRE,
                             __HIP_MEMORY_SCOPE_WORKGROUP) < 2u * (u + 1u)) {}
    f32x4 axh = *(const f32x4*)&xmbuf[p][w][2][l][0];
    {
      f32x4 xz = *(const f32x4*)&xmbuf[p][w][0][l][0];
      f32x4 xr = *(const f32x4*)&xmbuf[p][w][1][l][0];
      az[0] += xz[0]; az[1] += xz[1]; az[2] += xz[2]; az[3] += xz[3];
      ar[0] += xr[0]; ar[1] += xr[1]; ar[2] += xr[2]; ar[3] += xr[3];
    }
    __hip_atomic_fetch_add(&sv[4 + p], (l == 0) ? 1u : 0u, __ATOMIC_RELEASE,
                           __HIP_MEMORY_SCOPE_WORKGROUP);

    // ---- gates + reset; coherent h stores ----
    u16* hn = hws + (long)((t + 1) & 1) * H_ELEMS;
    float hnew_r[4];
    #pragma unroll
    for (int i = 0; i < 4; ++i) {
      int row = r0 + rsub + i;
      float z  = 1.0f / (1.0f + __expf(-(az[i] + bzs)));
      float rr = 1.0f / (1.0f + __expf(-(ar[i] + brs)));
      float tx = axh[i] + bxh + rr * (ahh[i] + bhh);
      tx = fminf(15.0f, fmaxf(-15.0f, tx));
      float e  = __expf(2.0f * tx);
      float hcand = (e - 1.0f) / (e + 1.0f);
      float hnew = z * hprev[i] + (1.0f - z) * hcand;
      hnew_r[i] = hnew;

      int sn = sarr[i] + 1;
      bool reset = (dlds[rsub + i][t] == 1) || ((sn & 15) == 0);
      float hkeep = reset ? 0.0f : hnew;
      sarr[i] = reset ? 0 : sn;
      hprev[i] = hkeep;
      if (t < NT - 1)
        store_h_coherent(hn + (long)row * UNITS + j, f2b(hkeep));
    }

    // ---- arrive: drain own h stores, publish THIS WAVE's flag ----
    if (t < NT - 1) {
      asm volatile("s_waitcnt vmcnt(0)" ::: "memory");
      if (l == 0) st_flag(myflag, (u32)(t + 1));
    }

    // ---- deferred outputs (off the inter-block critical path) ----
    #pragma unroll
    for (int i = 0; i < 4; ++i) {
      int row = r0 + rsub + i;
      long qo = ((long)row * NT + t) * UNITS + j;
      if (MODE) ((u16*)out)[qo] = f2b(hnew_r[i]);
      else      ((float*)out)[qo] = hnew_r[i];

      if (t == NT - 1) {
        long so = STATE_OFF + (long)row * UNITS + j;
        if (MODE) ((u16*)out)[so] = f2b(hprev[i]);
        else      ((float*)out)[so] = hprev[i];
        if (w == 0 && l15 == 0 && ug == 0) {
          long po = STEP_OFF + row;
          float sval = (float)sarr[i];
          if (MODE) ((u16*)out)[po] = f2b(sval);
          else      ((float*)out)[po] = sval;
        }
      }
    }
  }
}

extern "C" void kernel_launch(void* const* d_in, const int* in_sizes, int n_in,
                              void* d_out, int out_size, void* d_ws, size_t ws_size,
                              hipStream_t stream) {
  const void* xin    = d_in[0];
  const int*  dones  = (const int*)d_in[1];
  const void* stin   = d_in[2];
  const int*  stepin = (const int*)d_in[3];
  const void* W      = d_in[4];
  const void* U      = d_in[5];
  const void* bias   = d_in[6];

  sniff_init<<<1, 64, 0, stream>>>(W, (u32*)d_ws);
  h_init<<<256, 512, 0, stream>>>(stin, d_ws);
  gru_run<0><<<256, 256, 0, stream>>>(xin, dones, stepin, stin, W, U, bias, d_out, d_ws);
  gru_run<1><<<256, 256, 0, stream>>>(xin, dones, stepin, stin, W, U, bias, d_out, d_ws);
}